// Round 4
// baseline (147.710 us; speedup 1.0000x reference)
//
#include <hip/hip_runtime.h>
#include <math.h>

#define NB    512
#define NP    4096
#define BLOCK 256
#define NCHUNK (NP / BLOCK)     // 16 chunks per batch element

// fp32 sin, correctly rounded (via fp64 Taylor after exact revolution reduction).
// abs err ~1e-11 => rounds to the correctly-rounded fp32 everywhere that matters.
__device__ __forceinline__ float sin_cr(float tf) {
#pragma clang fp contract(off)
    double t  = (double)tf;
    double y  = t * 0.15915494309189535;    // t/(2pi), |y| <= ~60
    double f  = y - rint(y);                // [-0.5,0.5], exact subtraction
    double x  = f * 6.283185307179586;      // [-pi,pi]
    double x2 = x * x;
    double p;
    p =                  1.0 / 51090942171709440000.0;   // +1/21!
    p = fma(p, x2, -1.0 / 121645100408832000.0);         // -1/19!
    p = fma(p, x2,  1.0 / 355687428096000.0);            // +1/17!
    p = fma(p, x2, -1.0 / 1307674368000.0);              // -1/15!
    p = fma(p, x2,  1.0 / 6227020800.0);                 // +1/13!
    p = fma(p, x2, -1.0 / 39916800.0);                   // -1/11!
    p = fma(p, x2,  1.0 / 362880.0);                     // +1/9!
    p = fma(p, x2, -1.0 / 5040.0);                       // -1/7!
    p = fma(p, x2,  1.0 / 120.0);                        // +1/5!
    p = fma(p, x2, -1.0 / 6.0);                          // -1/3!
    double x3 = x2 * x;
    return (float)fma(p, x3, x);
}

// numpy einsum contig_contig_outstride0_two, baseline SSE2 npyv, n=20:
// products accumulate per-lane in columns of stride 4 (chained muladd = mul,add),
// horizontal sum tree (c0+c2)+(c1+c3). No FMA anywhere.
__device__ __forceinline__ float dot20_np(const float* __restrict__ wr,
                                          const float* __restrict__ h) {
#pragma clang fp contract(off)
    float c0 = wr[0] * h[0];
    float c1 = wr[1] * h[1];
    float c2 = wr[2] * h[2];
    float c3 = wr[3] * h[3];
    c0 = c0 + wr[4]  * h[4];   c1 = c1 + wr[5]  * h[5];
    c2 = c2 + wr[6]  * h[6];   c3 = c3 + wr[7]  * h[7];
    c0 = c0 + wr[8]  * h[8];   c1 = c1 + wr[9]  * h[9];
    c2 = c2 + wr[10] * h[10];  c3 = c3 + wr[11] * h[11];
    c0 = c0 + wr[12] * h[12];  c1 = c1 + wr[13] * h[13];
    c2 = c2 + wr[14] * h[14];  c3 = c3 + wr[15] * h[15];
    c0 = c0 + wr[16] * h[16];  c1 = c1 + wr[17] * h[17];
    c2 = c2 + wr[18] * h[18];  c3 = c3 + wr[19] * h[19];
    float s02 = c0 + c2;
    float s13 = c1 + c3;
    return s02 + s13;
}

// Param layout per batch (921 floats):
// [0,40) W1(20x2)  [40,60) b1 | [60,460) W2(20x20) [460,480) b2
// [480,880) W3(20x20) [880,900) b3 | [900,920) W4(1x20) [920] b4
__global__ __launch_bounds__(BLOCK) void siren20_np_kernel(
    const float* __restrict__ coords,
    const float* __restrict__ wflat,
    float* __restrict__ out)
{
#pragma clang fp contract(off)
    __shared__ float w[928];
    const int b   = blockIdx.y;
    const int tid = threadIdx.x;
    const float* wg = wflat + (size_t)b * 921;

    #pragma unroll
    for (int k = 0; k < 4; ++k) {
        int i = tid + k * BLOCK;
        if (i < 921) w[i] = wg[i];
    }
    __syncthreads();

    const int p = blockIdx.x * BLOCK + tid;
    const float2* cb = (const float2*)(coords + (size_t)b * NP * 2);
    const float2 c = cb[p];

    float h[20], g[20];

    // Layer 1: n=2 dot -> scalar loop, mul+add, NO fma. Then +b, *20, sin.
    #pragma unroll
    for (int j = 0; j < 20; ++j) {
        float s = w[2 * j] * c.x;
        s = s + w[2 * j + 1] * c.y;
        float u = s + w[40 + j];
        float t = 20.0f * u;
        h[j] = sin_cr(t);
    }

    // Layer 2: W at 60, b at 460
    #pragma unroll
    for (int j = 0; j < 20; ++j) {
        float a = dot20_np(&w[60 + 20 * j], h);
        float u = a + w[460 + j];
        float t = 20.0f * u;
        g[j] = sin_cr(t);
    }

    // Layer 3: W at 480, b at 880
    #pragma unroll
    for (int j = 0; j < 20; ++j) {
        float a = dot20_np(&w[480 + 20 * j], g);
        float u = a + w[880 + j];
        float t = 20.0f * u;
        h[j] = sin_cr(t);
    }

    // Layer 4: W at 900, b at 920, clip
    float a = dot20_np(&w[900], h);
    float u = a + w[920];
    u = fminf(fmaxf(u, 0.0f), 1.0f);

    out[(size_t)b * NP + p] = u;
}

extern "C" void kernel_launch(void* const* d_in, const int* in_sizes, int n_in,
                              void* d_out, int out_size, void* d_ws, size_t ws_size,
                              hipStream_t stream) {
    const float* coords = (const float*)d_in[0];
    const float* wflat  = (const float*)d_in[1];
    float* out = (float*)d_out;
    dim3 grid(NCHUNK, NB);
    siren20_np_kernel<<<grid, dim3(BLOCK), 0, stream>>>(coords, wflat, out);
}

// Round 5
// 131.550 us; speedup vs baseline: 1.1228x; 1.1228x over previous
//
#include <hip/hip_runtime.h>
#include <math.h>

#define NB    512
#define NP    4096
#define BLOCK 256
#define KPT   2
#define CHUNK (BLOCK * KPT)     // 512 points per block
#define NCHUNK (NP / CHUNK)     // 8 chunks per batch element

typedef float v2f __attribute__((ext_vector_type(2)));

// fp32 sin, correctly rounded (fp64 Taylor after exact revolution reduction).
// |t| <= ~450 here; abs err ~1e-11 -> rounds to correctly-rounded fp32.
__device__ __forceinline__ float sin_cr(float tf) {
#pragma clang fp contract(off)
    double t  = (double)tf;
    double y  = t * 0.15915494309189535;    // t/(2pi)
    double f  = y - rint(y);                // [-0.5,0.5], exact subtraction
    double x  = f * 6.283185307179586;      // [-pi,pi]
    double x2 = x * x;
    double p;
    p =                  1.0 / 51090942171709440000.0;   // +1/21!
    p = fma(p, x2, -1.0 / 121645100408832000.0);         // -1/19!
    p = fma(p, x2,  1.0 / 355687428096000.0);            // +1/17!
    p = fma(p, x2, -1.0 / 1307674368000.0);              // -1/15!
    p = fma(p, x2,  1.0 / 6227020800.0);                 // +1/13!
    p = fma(p, x2, -1.0 / 39916800.0);                   // -1/11!
    p = fma(p, x2,  1.0 / 362880.0);                     // +1/9!
    p = fma(p, x2, -1.0 / 5040.0);                       // -1/7!
    p = fma(p, x2,  1.0 / 120.0);                        // +1/5!
    p = fma(p, x2, -1.0 / 6.0);                          // -1/3!
    double x3 = x2 * x;
    return (float)fma(p, x3, x);
}

// numpy n=20 dot (SSE2 npyv, no FMA): 4 columns, chained mul+add per column,
// tree (c0+c2)+(c1+c3). Evaluated for 2 points at once (per-lane identical).
__device__ __forceinline__ v2f dot20_np2(const float* __restrict__ wr,
                                         const v2f* __restrict__ h) {
#pragma clang fp contract(off)
    v2f c0 = h[0] * wr[0];
    v2f c1 = h[1] * wr[1];
    v2f c2 = h[2] * wr[2];
    v2f c3 = h[3] * wr[3];
    c0 = c0 + h[4]  * wr[4];   c1 = c1 + h[5]  * wr[5];
    c2 = c2 + h[6]  * wr[6];   c3 = c3 + h[7]  * wr[7];
    c0 = c0 + h[8]  * wr[8];   c1 = c1 + h[9]  * wr[9];
    c2 = c2 + h[10] * wr[10];  c3 = c3 + h[11] * wr[11];
    c0 = c0 + h[12] * wr[12];  c1 = c1 + h[13] * wr[13];
    c2 = c2 + h[14] * wr[14];  c3 = c3 + h[15] * wr[15];
    c0 = c0 + h[16] * wr[16];  c1 = c1 + h[17] * wr[17];
    c2 = c2 + h[18] * wr[18];  c3 = c3 + h[19] * wr[19];
    v2f s02 = c0 + c2;
    v2f s13 = c1 + c3;
    return s02 + s13;
}

// Param layout per batch (921 floats):
// [0,40) W1(20x2)  [40,60) b1 | [60,460) W2(20x20) [460,480) b2
// [480,880) W3(20x20) [880,900) b3 | [900,920) W4(1x20) [920] b4
// Weights are wave-uniform (per-block batch) -> scalar (SMEM) loads, no LDS.
__global__ __launch_bounds__(BLOCK) void siren20_np2_kernel(
    const float* __restrict__ coords,
    const float* __restrict__ wflat,
    float* __restrict__ out)
{
#pragma clang fp contract(off)
    const int b   = blockIdx.y;
    const int tid = threadIdx.x;
    const float* __restrict__ w = wflat + (size_t)b * 921;

    const int p0 = blockIdx.x * CHUNK + tid;   // two coalesced points
    const int p1 = p0 + BLOCK;
    const float2* cbase = (const float2*)(coords + (size_t)b * NP * 2);
    const float2 ca = cbase[p0];
    const float2 cc = cbase[p1];
    v2f cx; cx.x = ca.x; cx.y = cc.x;
    v2f cy; cy.x = ca.y; cy.y = cc.y;

    v2f h[20], g[20];

    // Layer 1: n=2 scalar dot, mul+add (no fma), then +b, *20, sin.
    #pragma unroll
    for (int j = 0; j < 20; ++j) {
        v2f s = cx * w[2 * j];
        s = s + cy * w[2 * j + 1];
        v2f u = s + w[40 + j];
        v2f t = u * 20.0f;
        h[j].x = sin_cr(t.x);
        h[j].y = sin_cr(t.y);
    }

    // Layer 2: W at 60, b at 460
    #pragma unroll
    for (int j = 0; j < 20; ++j) {
        v2f a = dot20_np2(&w[60 + 20 * j], h);
        v2f u = a + w[460 + j];
        v2f t = u * 20.0f;
        g[j].x = sin_cr(t.x);
        g[j].y = sin_cr(t.y);
    }

    // Layer 3: W at 480, b at 880
    #pragma unroll
    for (int j = 0; j < 20; ++j) {
        v2f a = dot20_np2(&w[480 + 20 * j], g);
        v2f u = a + w[880 + j];
        v2f t = u * 20.0f;
        h[j].x = sin_cr(t.x);
        h[j].y = sin_cr(t.y);
    }

    // Layer 4: W at 900, b at 920, clip
    v2f a = dot20_np2(&w[900], h);
    v2f u = a + w[920];
    float r0 = fminf(fmaxf(u.x, 0.0f), 1.0f);
    float r1 = fminf(fmaxf(u.y, 0.0f), 1.0f);

    float* ob = out + (size_t)b * NP;
    ob[p0] = r0;
    ob[p1] = r1;
}

extern "C" void kernel_launch(void* const* d_in, const int* in_sizes, int n_in,
                              void* d_out, int out_size, void* d_ws, size_t ws_size,
                              hipStream_t stream) {
    const float* coords = (const float*)d_in[0];
    const float* wflat  = (const float*)d_in[1];
    float* out = (float*)d_out;
    dim3 grid(NCHUNK, NB);
    siren20_np2_kernel<<<grid, dim3(BLOCK), 0, stream>>>(coords, wflat, out);
}